// Round 2
// baseline (2410.309 us; speedup 1.0000x reference)
//
#include <hip/hip_runtime.h>
#include <cmath>

#define DIM    2048
#define NHEADS 16
#define HD     128
#define HIDDEN 8192
#define SEQ    2048
#define MTOK   4096   // BATCH*SEQ
#define EPS    1e-6f

typedef __bf16 bf16;
typedef __bf16 bf16x8 __attribute__((ext_vector_type(8)));
typedef __bf16 bf16x4 __attribute__((ext_vector_type(4)));
typedef float  f32x4  __attribute__((ext_vector_type(4)));

// async global->LDS, 16B per lane. LDS dest must be wave-uniform base; HW adds lane*16.
__device__ __forceinline__ void gl_lds16(const void* g, void* l) {
    __builtin_amdgcn_global_load_lds((const __attribute__((address_space(1))) void*)g,
                                     (__attribute__((address_space(3))) void*)l, 16, 0, 0);
}

// ---------------- transpose + fp32->bf16 convert: out[c][r] = in[r][c] ----------------
// 64x64 tiles, block (64,4)
__global__ void k_transpose_bf16(const float* __restrict__ in, bf16* __restrict__ out,
                                 int R, int C) {
    __shared__ float tile[64][65];
    int r0 = blockIdx.y * 64, c0 = blockIdx.x * 64;
    int tx = threadIdx.x, ty = threadIdx.y;
#pragma unroll
    for (int i = ty; i < 64; i += 4)
        tile[i][tx] = in[(size_t)(r0 + i) * C + (c0 + tx)];
    __syncthreads();
#pragma unroll
    for (int i = ty; i < 64; i += 4)
        out[(size_t)(c0 + i) * R + (r0 + tx)] = (bf16)tile[tx][i];
}

// ---------------- RMSNorm: fp32 in -> bf16 out ----------------
__global__ void k_rmsnorm(const float* __restrict__ x, const float* __restrict__ w,
                          bf16* __restrict__ out) {
    int row = blockIdx.x;
    int tid = threadIdx.x;
    const float4* xr = (const float4*)(x + (size_t)row * DIM);
    float4 a = xr[tid];
    float4 b = xr[tid + 256];
    float ss = a.x*a.x + a.y*a.y + a.z*a.z + a.w*a.w
             + b.x*b.x + b.y*b.y + b.z*b.z + b.w*b.w;
#pragma unroll
    for (int off = 32; off > 0; off >>= 1) ss += __shfl_down(ss, off, 64);
    __shared__ float red[4];
    if ((tid & 63) == 0) red[tid >> 6] = ss;
    __syncthreads();
    float tot = red[0] + red[1] + red[2] + red[3];
    float inv = rsqrtf(tot * (1.0f / DIM) + EPS);
    const float4* wr = (const float4*)w;
    float4 w0 = wr[tid], w1 = wr[tid + 256];
    bf16x4* o = (bf16x4*)(out + (size_t)row * DIM);
    bf16x4 v0, v1;
    v0[0] = (bf16)(a.x * inv * w0.x); v0[1] = (bf16)(a.y * inv * w0.y);
    v0[2] = (bf16)(a.z * inv * w0.z); v0[3] = (bf16)(a.w * inv * w0.w);
    v1[0] = (bf16)(b.x * inv * w1.x); v1[1] = (bf16)(b.y * inv * w1.y);
    v1[2] = (bf16)(b.z * inv * w1.z); v1[3] = (bf16)(b.w * inv * w1.w);
    o[tid] = v0;
    o[tid + 256] = v1;
}

// ---------------- GEMM: C[M][N] = A[M][K] @ B^T[N][K]  (bf16 in, fp32 accum) -------
// MODE 1: QKV fused, N=6144, route cols to oq/ok/ov ([MTOK][2048] each) + RoPE on q,k
// MODE 2: fp32 out with residual add: of = resid + A@B1^T
// MODE 3: dual-B: oq = silu(A@B1^T) * (A@B3^T), bf16
// m97 pattern: unpadded [128][64] LDS tiles, global_load_lds width-16 staging.
template<int MODE>
__global__ __launch_bounds__(256, MODE == 3 ? 3 : 4) void k_gemm(
    const bf16* __restrict__ A, const bf16* __restrict__ B1, const bf16* __restrict__ B2,
    const float* __restrict__ resid, const float* __restrict__ fcos,
    const float* __restrict__ fsin,
    bf16* __restrict__ oq, bf16* __restrict__ ok, bf16* __restrict__ ov,
    float* __restrict__ of, int M, int N, int K)
{
    __shared__ bf16 sm[(MODE == 3 ? 3 : 2) * 128 * 64];
    bf16* As  = sm;
    bf16* Bs1 = sm + 128 * 64;
    bf16* Bs2 = sm + 2 * 128 * 64;   // only valid for MODE==3

    const int tid  = threadIdx.x;
    const int wid  = tid >> 6;
    const int lane = tid & 63;
    const int quad = lane >> 4;
    const int l16  = lane & 15;
    const int wm   = wid >> 1;
    const int wn   = wid & 1;
    const int m0   = blockIdx.y * 128;
    const int n0   = blockIdx.x * 128;
    const int lr   = lane >> 3;          // 0..7 row within 8-row chunk
    const int lc   = (lane & 7) * 8;     // 0..56 elem col

    f32x4 acc1[4][4] = {};
    f32x4 acc2[4][4] = {};

    const int nk = K >> 6;
    for (int kt = 0; kt < nk; ++kt) {
        const int k0 = kt << 6;
        __syncthreads();
        // stage tiles: each wave stages rows [wid*32, wid*32+32), 4 issues of 8 rows
#pragma unroll
        for (int j = 0; j < 4; ++j) {
            const int rb = wid * 32 + j * 8;          // wave-uniform
            gl_lds16(&A [(size_t)(m0 + rb + lr) * K + k0 + lc], As  + rb * 64);
            gl_lds16(&B1[(size_t)(n0 + rb + lr) * K + k0 + lc], Bs1 + rb * 64);
            if (MODE == 3)
                gl_lds16(&B2[(size_t)(n0 + rb + lr) * K + k0 + lc], Bs2 + rb * 64);
        }
        __syncthreads();
#pragma unroll
        for (int kk = 0; kk < 64; kk += 32) {
            bf16x8 af[4], bf1[4], bf2[4];
#pragma unroll
            for (int i = 0; i < 4; ++i) {
                af[i]  = *(const bf16x8*)&As [(wm * 64 + i * 16 + l16) * 64 + kk + quad * 8];
                bf1[i] = *(const bf16x8*)&Bs1[(wn * 64 + i * 16 + l16) * 64 + kk + quad * 8];
                if (MODE == 3)
                    bf2[i] = *(const bf16x8*)&Bs2[(wn * 64 + i * 16 + l16) * 64 + kk + quad * 8];
            }
#pragma unroll
            for (int mi = 0; mi < 4; ++mi)
#pragma unroll
                for (int ni = 0; ni < 4; ++ni) {
                    acc1[mi][ni] = __builtin_amdgcn_mfma_f32_16x16x32_bf16(
                        af[mi], bf1[ni], acc1[mi][ni], 0, 0, 0);
                    if (MODE == 3)
                        acc2[mi][ni] = __builtin_amdgcn_mfma_f32_16x16x32_bf16(
                            af[mi], bf2[ni], acc2[mi][ni], 0, 0, 0);
                }
        }
    }

    // -------- epilogue --------
    if (MODE == 1) {
        // block's 128 cols live in exactly one of q/k/v (2048 each)
        const int region = n0 >> 11;
        bf16* dst = region == 0 ? oq : (region == 1 ? ok : ov);
        const int c0 = (n0 & 2047) + wn * 64;
#pragma unroll
        for (int mi = 0; mi < 4; ++mi)
#pragma unroll
            for (int i = 0; i < 4; ++i) {
                int row = m0 + wm * 64 + mi * 16 + quad * 4 + i;
                int pos = row & (SEQ - 1);
#pragma unroll
                for (int ni = 0; ni < 4; ++ni) {
                    int c = c0 + ni * 16 + l16;
                    float vA = acc1[mi][ni][i];
                    if (region < 2) {   // RoPE on q,k
                        float vB = __shfl_xor(vA, 1, 64);
                        int fi = (c & 127) >> 1;
                        float cs = fcos[pos * 64 + fi], sn = fsin[pos * 64 + fi];
                        vA = (l16 & 1) ? (vB * sn + vA * cs) : (vA * cs - vB * sn);
                    }
                    dst[(size_t)row * DIM + c] = (bf16)vA;
                }
            }
    } else {
#pragma unroll
        for (int mi = 0; mi < 4; ++mi)
#pragma unroll
            for (int i = 0; i < 4; ++i) {
                int row = m0 + wm * 64 + mi * 16 + quad * 4 + i;
#pragma unroll
                for (int ni = 0; ni < 4; ++ni) {
                    int col = n0 + wn * 64 + ni * 16 + l16;
                    float v1 = acc1[mi][ni][i];
                    if (MODE == 3) {
                        float v2 = acc2[mi][ni][i];
                        float g = v1 / (1.0f + __expf(-v1));
                        oq[(size_t)row * N + col] = (bf16)(g * v2);
                    } else {
                        of[(size_t)row * N + col] = resid[(size_t)row * N + col] + v1;
                    }
                }
            }
    }
}

// ---------------- Flash attention (causal), per (qtile, batch*head) -----------------
__global__ __launch_bounds__(256, 2) void k_flash(
    const bf16* __restrict__ q, const bf16* __restrict__ k,
    const bf16* __restrict__ v, bf16* __restrict__ o)
{
    const int qt = 15 - blockIdx.x;    // longest blocks first
    const int bh = blockIdx.y;
    const int b  = bh >> 4, h = bh & 15;
    const int tid  = threadIdx.x;
    const int wid  = tid >> 6, lane = tid & 63;
    const int quad = lane >> 4, l16 = lane & 15;

    __shared__ bf16 Ks [128][136];   // K tile [key][d]; reused as P tile [q][key]
    __shared__ bf16 Vts[128][136];   // V^T tile [d][key]

    const int q0 = qt * 128;
    const size_t baseQ  = ((size_t)b * SEQ + q0) * DIM + (size_t)h * HD;
    const size_t baseKV = ((size_t)b * SEQ) * DIM + (size_t)h * HD;

    bf16x8 qf[2][4];
#pragma unroll
    for (int mi = 0; mi < 2; ++mi)
#pragma unroll
        for (int ks = 0; ks < 4; ++ks)
            qf[mi][ks] = *(const bf16x8*)&q[baseQ +
                (size_t)(wid * 32 + mi * 16 + l16) * DIM + ks * 32 + quad * 8];

    f32x4 acc_o[2][8] = {};
    float m_run[2][4], l_run[2][4];
#pragma unroll
    for (int mi = 0; mi < 2; ++mi)
#pragma unroll
        for (int i = 0; i < 4; ++i) { m_run[mi][i] = -INFINITY; l_run[mi][i] = 0.f; }

    const float scale = 0.08838834764831845f;   // 1/sqrt(128)
    const int krow = tid >> 1, kcol = (tid & 1) * 64;

    for (int kt = 0; kt <= qt; ++kt) {
        const int kbase = kt * 128;
        __syncthreads();
#pragma unroll
        for (int j = 0; j < 8; ++j)
            *(uint4*)&Ks[krow][kcol + j * 8] =
                *(const uint4*)&k[baseKV + (size_t)(kbase + krow) * DIM + kcol + j * 8];
#pragma unroll
        for (int j = 0; j < 8; ++j) {
            bf16x8 vv = *(const bf16x8*)&v[baseKV + (size_t)(kbase + krow) * DIM + kcol + j * 8];
#pragma unroll
            for (int e = 0; e < 8; ++e)
                Vts[kcol + j * 8 + e][krow] = vv[e];
        }
        __syncthreads();

        f32x4 accs[2][8] = {};
#pragma unroll
        for (int ks = 0; ks < 4; ++ks)
#pragma unroll
            for (int ni = 0; ni < 8; ++ni) {
                bf16x8 kf = *(const bf16x8*)&Ks[ni * 16 + l16][ks * 32 + quad * 8];
#pragma unroll
                for (int mi = 0; mi < 2; ++mi)
                    accs[mi][ni] = __builtin_amdgcn_mfma_f32_16x16x32_bf16(
                        qf[mi][ks], kf, accs[mi][ni], 0, 0, 0);
            }

#pragma unroll
        for (int mi = 0; mi < 2; ++mi)
#pragma unroll
            for (int i = 0; i < 4; ++i) {
                int grow = q0 + wid * 32 + mi * 16 + quad * 4 + i;
                float mx = -INFINITY;
#pragma unroll
                for (int ni = 0; ni < 8; ++ni) {
                    float sv = accs[mi][ni][i] * scale;
                    int col = kbase + ni * 16 + l16;
                    if (col > grow) sv = -INFINITY;
                    accs[mi][ni][i] = sv;
                    mx = fmaxf(mx, sv);
                }
                mx = fmaxf(mx, __shfl_xor(mx, 1, 64));
                mx = fmaxf(mx, __shfl_xor(mx, 2, 64));
                mx = fmaxf(mx, __shfl_xor(mx, 4, 64));
                mx = fmaxf(mx, __shfl_xor(mx, 8, 64));
                float mnew  = fmaxf(m_run[mi][i], mx);
                float alpha = __expf(m_run[mi][i] - mnew);
                m_run[mi][i] = mnew;
                float rsum = 0.f;
#pragma unroll
                for (int ni = 0; ni < 8; ++ni) {
                    float p = __expf(accs[mi][ni][i] - mnew);
                    accs[mi][ni][i] = p;
                    rsum += p;
                }
                rsum += __shfl_xor(rsum, 1, 64);
                rsum += __shfl_xor(rsum, 2, 64);
                rsum += __shfl_xor(rsum, 4, 64);
                rsum += __shfl_xor(rsum, 8, 64);
                l_run[mi][i] = l_run[mi][i] * alpha + rsum;
#pragma unroll
                for (int ni = 0; ni < 8; ++ni) acc_o[mi][ni][i] *= alpha;
            }

        __syncthreads();
#pragma unroll
        for (int mi = 0; mi < 2; ++mi)
#pragma unroll
            for (int ni = 0; ni < 8; ++ni)
#pragma unroll
                for (int i = 0; i < 4; ++i)
                    Ks[wid * 32 + mi * 16 + quad * 4 + i][ni * 16 + l16] =
                        (bf16)accs[mi][ni][i];
        __syncthreads();

#pragma unroll
        for (int ks2 = 0; ks2 < 4; ++ks2) {
            bf16x8 pf[2];
#pragma unroll
            for (int mi = 0; mi < 2; ++mi)
                pf[mi] = *(const bf16x8*)&Ks[wid * 32 + mi * 16 + l16][ks2 * 32 + quad * 8];
#pragma unroll
            for (int ni = 0; ni < 8; ++ni) {
                bf16x8 vf = *(const bf16x8*)&Vts[ni * 16 + l16][ks2 * 32 + quad * 8];
#pragma unroll
                for (int mi = 0; mi < 2; ++mi)
                    acc_o[mi][ni] = __builtin_amdgcn_mfma_f32_16x16x32_bf16(
                        pf[mi], vf, acc_o[mi][ni], 0, 0, 0);
            }
        }
    }

#pragma unroll
    for (int mi = 0; mi < 2; ++mi)
#pragma unroll
        for (int i = 0; i < 4; ++i) {
            float invl = 1.0f / l_run[mi][i];
            int row = q0 + wid * 32 + mi * 16 + quad * 4 + i;
            size_t rb = ((size_t)b * SEQ + row) * DIM + (size_t)h * HD;
#pragma unroll
            for (int ni = 0; ni < 8; ++ni)
                o[rb + ni * 16 + l16] = (bf16)(acc_o[mi][ni][i] * invl);
        }
}

// ------------------------------- host launcher ---------------------------------------
extern "C" void kernel_launch(void* const* d_in, const int* in_sizes, int n_in,
                              void* d_out, int out_size, void* d_ws, size_t ws_size,
                              hipStream_t stream)
{
    (void)in_sizes; (void)n_in; (void)out_size; (void)ws_size;
    const float* x    = (const float*)d_in[0];
    const float* fcos = (const float*)d_in[1];
    const float* fsin = (const float*)d_in[2];
    const float* wq   = (const float*)d_in[4];
    const float* wk   = (const float*)d_in[5];
    const float* wv   = (const float*)d_in[6];
    const float* wo   = (const float*)d_in[7];
    const float* w1   = (const float*)d_in[8];
    const float* w2   = (const float*)d_in[9];
    const float* w3   = (const float*)d_in[10];
    const float* anw  = (const float*)d_in[11];
    const float* fnw  = (const float*)d_in[12];
    float* out = (float*)d_out;

    char* ws = (char*)d_ws;
    size_t off = 0;
    auto alloc = [&](size_t bytes) { void* p = ws + off; off += (bytes + 255) & ~255ull; return p; };
    bf16* wqT = (bf16*)alloc((size_t)DIM * DIM * 2);    // wq/wk/wv contiguous -> one B matrix
    bf16* wkT = (bf16*)alloc((size_t)DIM * DIM * 2);
    bf16* wvT = (bf16*)alloc((size_t)DIM * DIM * 2);
    bf16* woT = (bf16*)alloc((size_t)DIM * DIM * 2);
    bf16* w1T = (bf16*)alloc((size_t)HIDDEN * DIM * 2);
    bf16* w3T = (bf16*)alloc((size_t)HIDDEN * DIM * 2);
    bf16* xn  = (bf16*)alloc((size_t)MTOK * DIM * 2);   // also hn
    bf16* qb  = (bf16*)alloc((size_t)MTOK * DIM * 2);   // also attn out
    bf16* kb  = (bf16*)alloc((size_t)MTOK * DIM * 2);
    bf16* vb  = (bf16*)alloc((size_t)MTOK * DIM * 2);
    bf16* ffb = (bf16*)alloc((size_t)MTOK * HIDDEN * 2);
    bf16* w2T = kb;   // w2T [DIM][HIDDEN] reuses k+v region after attention

    dim3 tb(64, 4);
    k_transpose_bf16<<<dim3(DIM / 64, DIM / 64), tb, 0, stream>>>(wq, wqT, DIM, DIM);
    k_transpose_bf16<<<dim3(DIM / 64, DIM / 64), tb, 0, stream>>>(wk, wkT, DIM, DIM);
    k_transpose_bf16<<<dim3(DIM / 64, DIM / 64), tb, 0, stream>>>(wv, wvT, DIM, DIM);
    k_transpose_bf16<<<dim3(DIM / 64, DIM / 64), tb, 0, stream>>>(wo, woT, DIM, DIM);
    k_transpose_bf16<<<dim3(HIDDEN / 64, DIM / 64), tb, 0, stream>>>(w1, w1T, DIM, HIDDEN);
    k_transpose_bf16<<<dim3(HIDDEN / 64, DIM / 64), tb, 0, stream>>>(w3, w3T, DIM, HIDDEN);

    k_rmsnorm<<<MTOK, 256, 0, stream>>>(x, anw, xn);

    // fused QKV projection + RoPE (B = [wqT|wkT|wvT] contiguous, N=6144)
    k_gemm<1><<<dim3(3 * DIM / 128, MTOK / 128), 256, 0, stream>>>(
        xn, wqT, nullptr, nullptr, fcos, fsin, qb, kb, vb, nullptr, MTOK, 3 * DIM, DIM);

    // attention -> writes into qb
    k_flash<<<dim3(SEQ / 128, 2 * NHEADS), 256, 0, stream>>>(qb, kb, vb, qb);

    // w2 transpose into dead k/v region
    k_transpose_bf16<<<dim3(DIM / 64, HIDDEN / 64), tb, 0, stream>>>(w2, w2T, HIDDEN, DIM);

    // h = x + attn @ wo   (fp32, into d_out)
    k_gemm<2><<<dim3(DIM / 128, MTOK / 128), 256, 0, stream>>>(
        qb, woT, nullptr, x, nullptr, nullptr, nullptr, nullptr, nullptr, out, MTOK, DIM, DIM);

    k_rmsnorm<<<MTOK, 256, 0, stream>>>(out, fnw, xn);

    // ff = silu(hn@w1) * (hn@w3)
    k_gemm<3><<<dim3(HIDDEN / 128, MTOK / 128), 256, 0, stream>>>(
        xn, w1T, w3T, nullptr, nullptr, nullptr, ffb, nullptr, nullptr, nullptr,
        MTOK, HIDDEN, DIM);

    // out = h + ff @ w2
    k_gemm<2><<<dim3(DIM / 128, MTOK / 128), 256, 0, stream>>>(
        ffb, w2T, nullptr, out, nullptr, nullptr, nullptr, nullptr, nullptr, out,
        MTOK, DIM, HIDDEN);
}

// Round 3
// 1181.826 us; speedup vs baseline: 2.0395x; 2.0395x over previous
//
#include <hip/hip_runtime.h>
#include <cmath>

#define DIM    2048
#define NHEADS 16
#define HD     128
#define HIDDEN 8192
#define SEQ    2048
#define MTOK   4096   // BATCH*SEQ
#define EPS    1e-6f

typedef __bf16 bf16;
typedef __bf16 bf16x8 __attribute__((ext_vector_type(8)));
typedef __bf16 bf16x4 __attribute__((ext_vector_type(4)));
typedef float  f32x4  __attribute__((ext_vector_type(4)));

// ------- batched transpose + fp32->bf16 convert: out[c][r] = in[r][c], z picks matrix ----
__global__ void k_transpose4(const float* __restrict__ in0, const float* __restrict__ in1,
                             const float* __restrict__ in2, const float* __restrict__ in3,
                             bf16* __restrict__ o0, bf16* __restrict__ o1,
                             bf16* __restrict__ o2, bf16* __restrict__ o3,
                             int R, int C) {
    __shared__ float tile[64][65];
    const float* in = blockIdx.z == 0 ? in0 : blockIdx.z == 1 ? in1 : blockIdx.z == 2 ? in2 : in3;
    bf16* out       = blockIdx.z == 0 ? o0  : blockIdx.z == 1 ? o1  : blockIdx.z == 2 ? o2  : o3;
    int r0 = blockIdx.y * 64, c0 = blockIdx.x * 64;
    int tx = threadIdx.x, ty = threadIdx.y;
#pragma unroll
    for (int i = ty; i < 64; i += 4)
        tile[i][tx] = in[(size_t)(r0 + i) * C + (c0 + tx)];
    __syncthreads();
#pragma unroll
    for (int i = ty; i < 64; i += 4)
        out[(size_t)(c0 + i) * R + (r0 + tx)] = (bf16)tile[tx][i];
}

// ---------------- RMSNorm: fp32 in -> bf16 out ----------------
__global__ void k_rmsnorm(const float* __restrict__ x, const float* __restrict__ w,
                          bf16* __restrict__ out) {
    int row = blockIdx.x;
    int tid = threadIdx.x;
    const float4* xr = (const float4*)(x + (size_t)row * DIM);
    float4 a = xr[tid];
    float4 b = xr[tid + 256];
    float ss = a.x*a.x + a.y*a.y + a.z*a.z + a.w*a.w
             + b.x*b.x + b.y*b.y + b.z*b.z + b.w*b.w;
#pragma unroll
    for (int off = 32; off > 0; off >>= 1) ss += __shfl_down(ss, off, 64);
    __shared__ float red[4];
    if ((tid & 63) == 0) red[tid >> 6] = ss;
    __syncthreads();
    float tot = red[0] + red[1] + red[2] + red[3];
    float inv = rsqrtf(tot * (1.0f / DIM) + EPS);
    const float4* wr = (const float4*)w;
    float4 w0 = wr[tid], w1 = wr[tid + 256];
    bf16x4* o = (bf16x4*)(out + (size_t)row * DIM);
    bf16x4 v0, v1;
    v0[0] = (bf16)(a.x * inv * w0.x); v0[1] = (bf16)(a.y * inv * w0.y);
    v0[2] = (bf16)(a.z * inv * w0.z); v0[3] = (bf16)(a.w * inv * w0.w);
    v1[0] = (bf16)(b.x * inv * w1.x); v1[1] = (bf16)(b.y * inv * w1.y);
    v1[2] = (bf16)(b.z * inv * w1.z); v1[3] = (bf16)(b.w * inv * w1.w);
    o[tid] = v0;
    o[tid + 256] = v1;
}

// ---------------- GEMM: C[M][N] = A[M][K] @ B^T[N][K]  (bf16 in, fp32 accum) -------
// MODE 1: QKV fused (N=6144), route cols to oq/ok/ov ([MTOK][2048] each) + RoPE on q,k
// MODE 2: fp32 out with residual add: of = resid + A@B1^T
// MODE 3: dual-B: oq = silu(A@B1^T) * (A@B2^T), bf16
// Round-1 proven body: VGPR staging through padded [128][72] LDS tiles.
template<int MODE>
__global__ __launch_bounds__(256, 2) void k_gemm(
    const bf16* __restrict__ A, const bf16* __restrict__ B1, const bf16* __restrict__ B2,
    const float* __restrict__ resid, const float* __restrict__ fcos,
    const float* __restrict__ fsin,
    bf16* __restrict__ oq, bf16* __restrict__ ok, bf16* __restrict__ ov,
    float* __restrict__ of, int M, int N, int K)
{
    __shared__ bf16 As [128][72];
    __shared__ bf16 Bs1[128][72];
    __shared__ bf16 Bs2[MODE == 3 ? 128 : 1][72];

    const int tid  = threadIdx.x;
    const int wid  = tid >> 6;
    const int lane = tid & 63;
    const int quad = lane >> 4;
    const int l16  = lane & 15;
    const int wm   = wid >> 1;
    const int wn   = wid & 1;
    const int m0   = blockIdx.y * 128;
    const int n0   = blockIdx.x * 128;
    const int tr   = tid >> 3;         // 0..31
    const int tc   = (tid & 7) * 8;    // 0..56

    f32x4 acc1[4][4] = {};
    f32x4 acc2[4][4] = {};

    const int nk = K >> 6;
    for (int kt = 0; kt < nk; ++kt) {
        const int k0 = kt << 6;
        __syncthreads();
#pragma unroll
        for (int p = 0; p < 4; ++p) {
            int row = p * 32 + tr;
            *(uint4*)&As [row][tc] = *(const uint4*)&A [(size_t)(m0 + row) * K + k0 + tc];
            *(uint4*)&Bs1[row][tc] = *(const uint4*)&B1[(size_t)(n0 + row) * K + k0 + tc];
            if (MODE == 3)
                *(uint4*)&Bs2[row][tc] = *(const uint4*)&B2[(size_t)(n0 + row) * K + k0 + tc];
        }
        __syncthreads();
#pragma unroll
        for (int kk = 0; kk < 64; kk += 32) {
            bf16x8 af[4], bf1[4], bf2[4];
#pragma unroll
            for (int i = 0; i < 4; ++i) {
                af[i]  = *(const bf16x8*)&As [wm * 64 + i * 16 + l16][kk + quad * 8];
                bf1[i] = *(const bf16x8*)&Bs1[wn * 64 + i * 16 + l16][kk + quad * 8];
                if (MODE == 3)
                    bf2[i] = *(const bf16x8*)&Bs2[wn * 64 + i * 16 + l16][kk + quad * 8];
            }
#pragma unroll
            for (int mi = 0; mi < 4; ++mi)
#pragma unroll
                for (int ni = 0; ni < 4; ++ni) {
                    acc1[mi][ni] = __builtin_amdgcn_mfma_f32_16x16x32_bf16(
                        af[mi], bf1[ni], acc1[mi][ni], 0, 0, 0);
                    if (MODE == 3)
                        acc2[mi][ni] = __builtin_amdgcn_mfma_f32_16x16x32_bf16(
                            af[mi], bf2[ni], acc2[mi][ni], 0, 0, 0);
                }
        }
    }

    // -------- epilogue --------
    if (MODE == 1) {
        // block's 128 cols live in exactly one of q/k/v (2048 each)
        const int region = n0 >> 11;
        bf16* dst = region == 0 ? oq : (region == 1 ? ok : ov);
        const int c0 = (n0 & 2047) + wn * 64;
#pragma unroll
        for (int mi = 0; mi < 4; ++mi)
#pragma unroll
            for (int i = 0; i < 4; ++i) {
                int row = m0 + wm * 64 + mi * 16 + quad * 4 + i;
                int pos = row & (SEQ - 1);
#pragma unroll
                for (int ni = 0; ni < 4; ++ni) {
                    int c = c0 + ni * 16 + l16;
                    float vA = acc1[mi][ni][i];
                    if (region < 2) {   // RoPE on q,k
                        float vB = __shfl_xor(vA, 1, 64);
                        int fi = (c & 127) >> 1;
                        float cs = fcos[pos * 64 + fi], sn = fsin[pos * 64 + fi];
                        vA = (l16 & 1) ? (vB * sn + vA * cs) : (vA * cs - vB * sn);
                    }
                    dst[(size_t)row * DIM + c] = (bf16)vA;
                }
            }
    } else {
#pragma unroll
        for (int mi = 0; mi < 4; ++mi)
#pragma unroll
            for (int i = 0; i < 4; ++i) {
                int row = m0 + wm * 64 + mi * 16 + quad * 4 + i;
#pragma unroll
                for (int ni = 0; ni < 4; ++ni) {
                    int col = n0 + wn * 64 + ni * 16 + l16;
                    float v1 = acc1[mi][ni][i];
                    if (MODE == 3) {
                        float v2 = acc2[mi][ni][i];
                        float g = v1 / (1.0f + __expf(-v1));
                        oq[(size_t)row * N + col] = (bf16)(g * v2);
                    } else {
                        of[(size_t)row * N + col] = resid[(size_t)row * N + col] + v1;
                    }
                }
            }
    }
}

// ---------------- Flash attention (causal), per (qtile, batch*head) -----------------
__global__ __launch_bounds__(256, 2) void k_flash(
    const bf16* __restrict__ q, const bf16* __restrict__ k,
    const bf16* __restrict__ v, bf16* __restrict__ o)
{
    const int qt = 15 - blockIdx.x;    // longest blocks first
    const int bh = blockIdx.y;
    const int b  = bh >> 4, h = bh & 15;
    const int tid  = threadIdx.x;
    const int wid  = tid >> 6, lane = tid & 63;
    const int quad = lane >> 4, l16 = lane & 15;

    __shared__ bf16 Ks [128][136];   // K tile [key][d]; reused as P tile [q][key]
    __shared__ bf16 Vts[128][136];   // V^T tile [d][key]

    const int q0 = qt * 128;
    const size_t baseQ  = ((size_t)b * SEQ + q0) * DIM + (size_t)h * HD;
    const size_t baseKV = ((size_t)b * SEQ) * DIM + (size_t)h * HD;

    bf16x8 qf[2][4];
#pragma unroll
    for (int mi = 0; mi < 2; ++mi)
#pragma unroll
        for (int ks = 0; ks < 4; ++ks)
            qf[mi][ks] = *(const bf16x8*)&q[baseQ +
                (size_t)(wid * 32 + mi * 16 + l16) * DIM + ks * 32 + quad * 8];

    f32x4 acc_o[2][8] = {};
    float m_run[2][4], l_run[2][4];
#pragma unroll
    for (int mi = 0; mi < 2; ++mi)
#pragma unroll
        for (int i = 0; i < 4; ++i) { m_run[mi][i] = -INFINITY; l_run[mi][i] = 0.f; }

    const float scale = 0.08838834764831845f;   // 1/sqrt(128)
    const int krow = tid >> 1, kcol = (tid & 1) * 64;

    for (int kt = 0; kt <= qt; ++kt) {
        const int kbase = kt * 128;
        __syncthreads();
#pragma unroll
        for (int j = 0; j < 8; ++j)
            *(uint4*)&Ks[krow][kcol + j * 8] =
                *(const uint4*)&k[baseKV + (size_t)(kbase + krow) * DIM + kcol + j * 8];
#pragma unroll
        for (int j = 0; j < 8; ++j) {
            bf16x8 vv = *(const bf16x8*)&v[baseKV + (size_t)(kbase + krow) * DIM + kcol + j * 8];
#pragma unroll
            for (int e = 0; e < 8; ++e)
                Vts[kcol + j * 8 + e][krow] = vv[e];
        }
        __syncthreads();

        f32x4 accs[2][8] = {};
#pragma unroll
        for (int ks = 0; ks < 4; ++ks)
#pragma unroll
            for (int ni = 0; ni < 8; ++ni) {
                bf16x8 kf = *(const bf16x8*)&Ks[ni * 16 + l16][ks * 32 + quad * 8];
#pragma unroll
                for (int mi = 0; mi < 2; ++mi)
                    accs[mi][ni] = __builtin_amdgcn_mfma_f32_16x16x32_bf16(
                        qf[mi][ks], kf, accs[mi][ni], 0, 0, 0);
            }

#pragma unroll
        for (int mi = 0; mi < 2; ++mi)
#pragma unroll
            for (int i = 0; i < 4; ++i) {
                int grow = q0 + wid * 32 + mi * 16 + quad * 4 + i;
                float mx = -INFINITY;
#pragma unroll
                for (int ni = 0; ni < 8; ++ni) {
                    float sv = accs[mi][ni][i] * scale;
                    int col = kbase + ni * 16 + l16;
                    if (col > grow) sv = -INFINITY;
                    accs[mi][ni][i] = sv;
                    mx = fmaxf(mx, sv);
                }
                mx = fmaxf(mx, __shfl_xor(mx, 1, 64));
                mx = fmaxf(mx, __shfl_xor(mx, 2, 64));
                mx = fmaxf(mx, __shfl_xor(mx, 4, 64));
                mx = fmaxf(mx, __shfl_xor(mx, 8, 64));
                float mnew  = fmaxf(m_run[mi][i], mx);
                float alpha = __expf(m_run[mi][i] - mnew);
                m_run[mi][i] = mnew;
                float rsum = 0.f;
#pragma unroll
                for (int ni = 0; ni < 8; ++ni) {
                    float p = __expf(accs[mi][ni][i] - mnew);
                    accs[mi][ni][i] = p;
                    rsum += p;
                }
                rsum += __shfl_xor(rsum, 1, 64);
                rsum += __shfl_xor(rsum, 2, 64);
                rsum += __shfl_xor(rsum, 4, 64);
                rsum += __shfl_xor(rsum, 8, 64);
                l_run[mi][i] = l_run[mi][i] * alpha + rsum;
#pragma unroll
                for (int ni = 0; ni < 8; ++ni) acc_o[mi][ni][i] *= alpha;
            }

        __syncthreads();
#pragma unroll
        for (int mi = 0; mi < 2; ++mi)
#pragma unroll
            for (int ni = 0; ni < 8; ++ni)
#pragma unroll
                for (int i = 0; i < 4; ++i)
                    Ks[wid * 32 + mi * 16 + quad * 4 + i][ni * 16 + l16] =
                        (bf16)accs[mi][ni][i];
        __syncthreads();

#pragma unroll
        for (int ks2 = 0; ks2 < 4; ++ks2) {
            bf16x8 pf[2];
#pragma unroll
            for (int mi = 0; mi < 2; ++mi)
                pf[mi] = *(const bf16x8*)&Ks[wid * 32 + mi * 16 + l16][ks2 * 32 + quad * 8];
#pragma unroll
            for (int ni = 0; ni < 8; ++ni) {
                bf16x8 vf = *(const bf16x8*)&Vts[ni * 16 + l16][ks2 * 32 + quad * 8];
#pragma unroll
                for (int mi = 0; mi < 2; ++mi)
                    acc_o[mi][ni] = __builtin_amdgcn_mfma_f32_16x16x32_bf16(
                        pf[mi], vf, acc_o[mi][ni], 0, 0, 0);
            }
        }
    }

#pragma unroll
    for (int mi = 0; mi < 2; ++mi)
#pragma unroll
        for (int i = 0; i < 4; ++i) {
            float invl = 1.0f / l_run[mi][i];
            int row = q0 + wid * 32 + mi * 16 + quad * 4 + i;
            size_t rb = ((size_t)b * SEQ + row) * DIM + (size_t)h * HD;
#pragma unroll
            for (int ni = 0; ni < 8; ++ni)
                o[rb + ni * 16 + l16] = (bf16)(acc_o[mi][ni][i] * invl);
        }
}

// ------------------------------- host launcher ---------------------------------------
extern "C" void kernel_launch(void* const* d_in, const int* in_sizes, int n_in,
                              void* d_out, int out_size, void* d_ws, size_t ws_size,
                              hipStream_t stream)
{
    (void)in_sizes; (void)n_in; (void)out_size; (void)ws_size;
    const float* x    = (const float*)d_in[0];
    const float* fcos = (const float*)d_in[1];
    const float* fsin = (const float*)d_in[2];
    const float* wq   = (const float*)d_in[4];
    const float* wk   = (const float*)d_in[5];
    const float* wv   = (const float*)d_in[6];
    const float* wo   = (const float*)d_in[7];
    const float* w1   = (const float*)d_in[8];
    const float* w2   = (const float*)d_in[9];
    const float* w3   = (const float*)d_in[10];
    const float* anw  = (const float*)d_in[11];
    const float* fnw  = (const float*)d_in[12];
    float* out = (float*)d_out;

    char* ws = (char*)d_ws;
    size_t off = 0;
    auto alloc = [&](size_t bytes) { void* p = ws + off; off += (bytes + 255) & ~255ull; return p; };
    bf16* wqT = (bf16*)alloc((size_t)DIM * DIM * 2);    // wq/wk/wv contiguous -> one B matrix
    bf16* wkT = (bf16*)alloc((size_t)DIM * DIM * 2);
    bf16* wvT = (bf16*)alloc((size_t)DIM * DIM * 2);
    bf16* woT = (bf16*)alloc((size_t)DIM * DIM * 2);
    bf16* w1T = (bf16*)alloc((size_t)HIDDEN * DIM * 2);
    bf16* w3T = (bf16*)alloc((size_t)HIDDEN * DIM * 2);
    bf16* xn  = (bf16*)alloc((size_t)MTOK * DIM * 2);   // also hn
    bf16* qb  = (bf16*)alloc((size_t)MTOK * DIM * 2);   // also attn out
    bf16* kb  = (bf16*)alloc((size_t)MTOK * DIM * 2);
    bf16* vb  = (bf16*)alloc((size_t)MTOK * DIM * 2);
    bf16* ffb = (bf16*)alloc((size_t)MTOK * HIDDEN * 2);
    bf16* w2T = kb;   // w2T [DIM][HIDDEN] reuses k+v region after attention

    dim3 tb(64, 4);
    // all four DIM x DIM weight transposes in ONE dispatch
    k_transpose4<<<dim3(DIM / 64, DIM / 64, 4), tb, 0, stream>>>(
        wq, wk, wv, wo, wqT, wkT, wvT, woT, DIM, DIM);
    // w1 + w3 in one dispatch
    k_transpose4<<<dim3(HIDDEN / 64, DIM / 64, 2), tb, 0, stream>>>(
        w1, w3, nullptr, nullptr, w1T, w3T, nullptr, nullptr, DIM, HIDDEN);

    k_rmsnorm<<<MTOK, 256, 0, stream>>>(x, anw, xn);

    // fused QKV projection + RoPE (B = [wqT|wkT|wvT] contiguous, N=6144)
    k_gemm<1><<<dim3(3 * DIM / 128, MTOK / 128), 256, 0, stream>>>(
        xn, wqT, nullptr, nullptr, fcos, fsin, qb, kb, vb, nullptr, MTOK, 3 * DIM, DIM);

    // attention -> writes into qb
    k_flash<<<dim3(SEQ / 128, 2 * NHEADS), 256, 0, stream>>>(qb, kb, vb, qb);

    // w2 transpose into dead k/v region (after flash; aliases kb)
    k_transpose4<<<dim3(DIM / 64, HIDDEN / 64, 1), tb, 0, stream>>>(
        w2, nullptr, nullptr, nullptr, w2T, nullptr, nullptr, nullptr, HIDDEN, DIM);

    // h = x + attn @ wo   (fp32, into d_out)
    k_gemm<2><<<dim3(DIM / 128, MTOK / 128), 256, 0, stream>>>(
        qb, woT, nullptr, x, nullptr, nullptr, nullptr, nullptr, nullptr, out, MTOK, DIM, DIM);

    k_rmsnorm<<<MTOK, 256, 0, stream>>>(out, fnw, xn);

    // ff = silu(hn@w1) * (hn@w3)
    k_gemm<3><<<dim3(HIDDEN / 128, MTOK / 128), 256, 0, stream>>>(
        xn, w1T, w3T, nullptr, nullptr, nullptr, ffb, nullptr, nullptr, nullptr,
        MTOK, HIDDEN, DIM);

    // out = h + ff @ w2
    k_gemm<2><<<dim3(DIM / 128, MTOK / 128), 256, 0, stream>>>(
        ffb, w2T, nullptr, out, nullptr, nullptr, nullptr, nullptr, nullptr, out,
        MTOK, DIM, HIDDEN);
}